// Round 1
// baseline (1137.084 us; speedup 1.0000x reference)
//
#include <hip/hip_runtime.h>
#include <math.h>

constexpr int NB   = 4;
constexpr int LL   = 8192;
constexpr int DD   = 256;
constexpr int NH   = 8;
constexpr int HDIM = 32;
constexpr int WNN  = 9;
constexpr int PPAD = 4;

constexpr int CH  = 8;        // windows per attention block
constexpr int RS  = CH + 8;   // 16 staged rows
constexpr int SQS = 260;      // padded LDS stride for sq/sk/pq/pk (bank rotation, keeps 16B align)
constexpr int ARS = 260;      // padded stride for attn_res tile in out_kernel

// ---------------- pos projection: posq/posk/posv = pos @ W ----------------
__global__ __launch_bounds__(256) void pos_proj(
    const float* __restrict__ pos,
    const float* __restrict__ Wq, const float* __restrict__ Wk, const float* __restrict__ Wv,
    float* __restrict__ PQ, float* __restrict__ PK, float* __restrict__ PV) {
  __shared__ float ps[WNN * DD];
  const int t = threadIdx.x;
  for (int w = 0; w < WNN; ++w) ps[w * DD + t] = pos[w * DD + t];
  __syncthreads();
  for (int w = 0; w < WNN; ++w) {
    float aq = 0.f, ak = 0.f, av = 0.f;
    for (int d = 0; d < DD; ++d) {
      float p = ps[w * DD + d];
      aq += p * Wq[d * DD + t];
      ak += p * Wk[d * DD + t];
      av += p * Wv[d * DD + t];
    }
    PQ[w * DD + t] = aq; PK[w * DD + t] = ak; PV[w * DD + t] = av;
  }
}

// ---------------- QKV projection: XQ/XK/XV = x @ W ----------------
// grid (1024 row-tiles, 3 weights), 32 rows/block, thread t owns column t
__global__ __launch_bounds__(256) void qkv_proj(
    const float* __restrict__ x,
    const float* __restrict__ Wq, const float* __restrict__ Wk, const float* __restrict__ Wv,
    float* __restrict__ XQ, float* __restrict__ XK, float* __restrict__ XV) {
  __shared__ float xs[32 * 256];
  const int t = threadIdx.x;
  const size_t row0 = (size_t)blockIdx.x * 32;
  const int which = blockIdx.y;
  const float* W = (which == 0) ? Wq : (which == 1) ? Wk : Wv;
  float* O = (which == 0) ? XQ : (which == 1) ? XK : XV;

  const float4* xg = (const float4*)(x + row0 * 256);
  float4* xs4 = (float4*)xs;
#pragma unroll
  for (int i = 0; i < 8; ++i) xs4[t + i * 256] = xg[t + i * 256];
  __syncthreads();

  float acc[32];
#pragma unroll
  for (int m = 0; m < 32; ++m) acc[m] = 0.f;
  for (int d0 = 0; d0 < 256; d0 += 4) {
    float w0 = W[(d0 + 0) * 256 + t];
    float w1 = W[(d0 + 1) * 256 + t];
    float w2 = W[(d0 + 2) * 256 + t];
    float w3 = W[(d0 + 3) * 256 + t];
#pragma unroll
    for (int m = 0; m < 32; ++m) {
      float4 a = *(const float4*)&xs[m * 256 + d0];   // broadcast read — conflict-free
      acc[m] += a.x * w0 + a.y * w1 + a.z * w2 + a.w * w3;
    }
  }
#pragma unroll
  for (int m = 0; m < 32; ++m) O[(row0 + m) * 256 + t] = acc[m];
}

// ---------------- windowed attention → CTX ----------------
__global__ __launch_bounds__(256) void attn_kernel(
    const float* __restrict__ XQ, const float* __restrict__ XK, const float* __restrict__ XV,
    const float* __restrict__ PQ, const float* __restrict__ PK, const float* __restrict__ PV,
    float* __restrict__ CTX) {
  __shared__ float sq[RS * SQS];
  __shared__ float sk[RS * SQS];
  __shared__ float sv[RS * 256];
  __shared__ float pq[WNN * SQS];
  __shared__ float pk[WNN * SQS];
  __shared__ float pv[WNN * 256];
  __shared__ float asum[CH * NH * WNN];

  const int t = threadIdx.x;
  const int nblk = LL / CH;
  const int b = blockIdx.x / nblk;
  const int n0 = (blockIdx.x % nblk) * CH;
  const size_t base = (size_t)b * LL * DD;

  for (int w = 0; w < WNN; ++w) {
    pq[w * SQS + t] = PQ[w * DD + t];
    pk[w * SQS + t] = PK[w * DD + t];
    pv[w * 256 + t] = PV[w * DD + t];
  }
  for (int r = 0; r < RS; ++r) {
    int j = n0 - PPAD + r;
    float vq = 0.f, vk = 0.f, vv = 0.f;
    if (j >= 0 && j < LL) {
      size_t off = base + (size_t)j * DD + t;
      vq = XQ[off]; vk = XK[off]; vv = XV[off];
    }
    sq[r * SQS + t] = vq;
    sk[r * SQS + t] = vk;
    sv[r * 256 + t] = vv;
  }
  for (int i = t; i < CH * NH * WNN; i += 256) asum[i] = 0.f;
  __syncthreads();

  // 192 active threads: (nl, h, qg) — each handles 3 query rows, all 9 keys
  if (t < CH * NH * 3) {
    const int nl = t / 24;
    const int rem = t % 24;
    const int h = rem / 3;
    const int qg = rem % 3;
    float4 qv[3][8];
#pragma unroll
    for (int j = 0; j < 3; ++j) {
      const int qi = qg * 3 + j;
      const float4* qrow = (const float4*)&sq[(nl + qi) * SQS + h * HDIM];
      const float4* prow = (const float4*)&pq[qi * SQS + h * HDIM];
#pragma unroll
      for (int i = 0; i < 8; ++i) {
        float4 a = qrow[i], p = prow[i];
        qv[j][i] = make_float4(a.x + p.x, a.y + p.y, a.z + p.z, a.w + p.w);
      }
    }
    float sc[3][9];
#pragma unroll
    for (int ki = 0; ki < WNN; ++ki) {
      const float4* krow = (const float4*)&sk[(nl + ki) * SQS + h * HDIM];
      const float4* pkr  = (const float4*)&pk[ki * SQS + h * HDIM];
      float4 kv[8];
#pragma unroll
      for (int i = 0; i < 8; ++i) {
        float4 a = krow[i], p = pkr[i];
        kv[i] = make_float4(a.x + p.x, a.y + p.y, a.z + p.z, a.w + p.w);
      }
#pragma unroll
      for (int j = 0; j < 3; ++j) {
        float acc = 0.f;
#pragma unroll
        for (int i = 0; i < 8; ++i)
          acc += qv[j][i].x * kv[i].x + qv[j][i].y * kv[i].y +
                 qv[j][i].z * kv[i].z + qv[j][i].w * kv[i].w;
        sc[j][ki] = acc * 0.17677669529663687f;  // 1/sqrt(32)
      }
    }
#pragma unroll
    for (int j = 0; j < 3; ++j) {
      float mx = sc[j][0];
#pragma unroll
      for (int ki = 1; ki < WNN; ++ki) mx = fmaxf(mx, sc[j][ki]);
      float sum = 0.f;
#pragma unroll
      for (int ki = 0; ki < WNN; ++ki) { sc[j][ki] = __expf(sc[j][ki] - mx); sum += sc[j][ki]; }
      float inv = 1.f / sum;
#pragma unroll
      for (int ki = 0; ki < WNN; ++ki)
        atomicAdd(&asum[(nl * NH + h) * WNN + ki], sc[j][ki] * inv);
    }
  }
  __syncthreads();

  // ctx[d] = sum_k asum[h,k] * (xv[row]+posv[k])[d]
  const int h = t >> 5;
  for (int nl = 0; nl < CH; ++nl) {
    float acc = 0.f;
#pragma unroll
    for (int ki = 0; ki < WNN; ++ki)
      acc += asum[(nl * NH + h) * WNN + ki] * (sv[(nl + ki) * 256 + t] + pv[ki * 256 + t]);
    CTX[base + (size_t)(n0 + nl) * DD + t] = acc;
  }
}

// ---------------- fused: LN1(x + ctx@Wo) -> LN2(ar@Wout^T + b + ar) -> relu ----------------
__global__ __launch_bounds__(256) void out_kernel(
    const float* __restrict__ CTX, const float* __restrict__ X,
    const float* __restrict__ Wo, const float* __restrict__ Wout,
    const float* __restrict__ bo,
    const float* __restrict__ g1, const float* __restrict__ b1,
    const float* __restrict__ g2, const float* __restrict__ b2,
    float* __restrict__ out) {
  __shared__ float ar[32 * ARS];
  __shared__ float wu[256 * 36];   // union: ctx tile (stride 256) then Wout^T tile (stride 36)
  __shared__ float ps1[32][8], ps2[32][8];
  __shared__ float ms[32], rs[32];
  const int t = threadIdx.x;
  const size_t row0 = (size_t)blockIdx.x * 32;

  {
    const float4* cg = (const float4*)(CTX + row0 * 256);
    float4* ct4 = (float4*)wu;
#pragma unroll
    for (int i = 0; i < 8; ++i) ct4[t + i * 256] = cg[t + i * 256];
  }
  __syncthreads();

  // GEMM1: acc[m] = sum_d ctx[m][d] * Wo[d][t]
  float acc[32];
#pragma unroll
  for (int m = 0; m < 32; ++m) acc[m] = 0.f;
  for (int d0 = 0; d0 < 256; d0 += 4) {
    float w0 = Wo[(d0 + 0) * 256 + t];
    float w1 = Wo[(d0 + 1) * 256 + t];
    float w2 = Wo[(d0 + 2) * 256 + t];
    float w3 = Wo[(d0 + 3) * 256 + t];
#pragma unroll
    for (int m = 0; m < 32; ++m) {
      float4 a = *(const float4*)&wu[m * 256 + d0];
      acc[m] += a.x * w0 + a.y * w1 + a.z * w2 + a.w * w3;
    }
  }
#pragma unroll
  for (int m = 0; m < 32; ++m)
    ar[m * ARS + t] = acc[m] + X[(row0 + m) * 256 + t];
  __syncthreads();

  // LN1 stats
  {
    const int row = t & 31, seg = t >> 5;
    float s1 = 0.f, s2 = 0.f;
#pragma unroll
    for (int i = 0; i < 8; ++i) {
      float4 v = *(const float4*)&ar[row * ARS + seg * 32 + i * 4];
      s1 += v.x + v.y + v.z + v.w;
      s2 += v.x * v.x + v.y * v.y + v.z * v.z + v.w * v.w;
    }
    ps1[row][seg] = s1; ps2[row][seg] = s2;
  }
  __syncthreads();
  if (t < 32) {
    float s1 = 0.f, s2 = 0.f;
#pragma unroll
    for (int s = 0; s < 8; ++s) { s1 += ps1[t][s]; s2 += ps2[t][s]; }
    float mean = s1 * (1.f / 256.f);
    float var = s2 * (1.f / 256.f) - mean * mean;
    ms[t] = mean; rs[t] = rsqrtf(var + 1e-5f);
  }
  __syncthreads();
  {
    const float g1v = g1[t], b1v = b1[t];
#pragma unroll
    for (int m = 0; m < 32; ++m)
      ar[m * ARS + t] = (ar[m * ARS + t] - ms[m]) * rs[m] * g1v + b1v;
  }

  // GEMM2: acc2[m] = sum_d ar[m][d] * Wout[t][d], staged transposed tiles
  float acc2[32];
#pragma unroll
  for (int m = 0; m < 32; ++m) acc2[m] = 0.f;
  for (int d0 = 0; d0 < 256; d0 += 32) {
    __syncthreads();
#pragma unroll
    for (int i = 0; i < 32; ++i) {
      int f = i * 256 + t;
      int e = f >> 5, dd = f & 31;
      wu[e * 36 + dd] = Wout[e * 256 + d0 + dd];
    }
    __syncthreads();
#pragma unroll
    for (int dd = 0; dd < 32; dd += 4) {
      float4 wv = *(const float4*)&wu[t * 36 + dd];
#pragma unroll
      for (int m = 0; m < 32; ++m) {
        float4 a = *(const float4*)&ar[m * ARS + d0 + dd];
        acc2[m] += a.x * wv.x + a.y * wv.y + a.z * wv.z + a.w * wv.w;
      }
    }
  }
  __syncthreads();
  {
    const float bov = bo[t];
#pragma unroll
    for (int m = 0; m < 32; ++m)
      ar[m * ARS + t] = acc2[m] + bov + ar[m * ARS + t];  // thread-private slot, no race
  }
  __syncthreads();

  // LN2 stats
  {
    const int row = t & 31, seg = t >> 5;
    float s1 = 0.f, s2 = 0.f;
#pragma unroll
    for (int i = 0; i < 8; ++i) {
      float4 v = *(const float4*)&ar[row * ARS + seg * 32 + i * 4];
      s1 += v.x + v.y + v.z + v.w;
      s2 += v.x * v.x + v.y * v.y + v.z * v.z + v.w * v.w;
    }
    ps1[row][seg] = s1; ps2[row][seg] = s2;
  }
  __syncthreads();
  if (t < 32) {
    float s1 = 0.f, s2 = 0.f;
#pragma unroll
    for (int s = 0; s < 8; ++s) { s1 += ps1[t][s]; s2 += ps2[t][s]; }
    float mean = s1 * (1.f / 256.f);
    float var = s2 * (1.f / 256.f) - mean * mean;
    ms[t] = mean; rs[t] = rsqrtf(var + 1e-5f);
  }
  __syncthreads();
  {
    const float g2v = g2[t], b2v = b2[t];
#pragma unroll
    for (int m = 0; m < 32; ++m) {
      float v = (ar[m * ARS + t] - ms[m]) * rs[m] * g2v + b2v;
      out[(row0 + m) * 256 + t] = fmaxf(v, 0.f);
    }
  }
}

extern "C" void kernel_launch(void* const* d_in, const int* in_sizes, int n_in,
                              void* d_out, int out_size, void* d_ws, size_t ws_size,
                              hipStream_t stream) {
  const float* x    = (const float*)d_in[0];
  const float* Wq   = (const float*)d_in[1];
  const float* Wk   = (const float*)d_in[2];
  const float* Wv   = (const float*)d_in[3];
  const float* Wo   = (const float*)d_in[4];
  const float* pos  = (const float*)d_in[5];
  const float* Wout = (const float*)d_in[6];
  const float* bo   = (const float*)d_in[7];
  const float* g1   = (const float*)d_in[8];
  const float* b1   = (const float*)d_in[9];
  const float* g2   = (const float*)d_in[10];
  const float* b2   = (const float*)d_in[11];
  float* out = (float*)d_out;

  const size_t nrows = (size_t)NB * LL;  // 32768
  float* ws = (float*)d_ws;
  float* XQ = ws;                        // 32768*256 f32 each (3 x 32 MB)
  float* XK = XQ + nrows * DD;
  float* XV = XK + nrows * DD;
  float* PQ = XV + nrows * DD;           // 9*256 each
  float* PK = PQ + WNN * DD;
  float* PV = PK + WNN * DD;
  float* CTX = out;                      // reuse output buffer (block-local read->overwrite in out_kernel)

  pos_proj<<<1, 256, 0, stream>>>(pos, Wq, Wk, Wv, PQ, PK, PV);
  qkv_proj<<<dim3((unsigned)(nrows / 32), 3), 256, 0, stream>>>(x, Wq, Wk, Wv, XQ, XK, XV);
  attn_kernel<<<NB * (LL / CH), 256, 0, stream>>>(XQ, XK, XV, PQ, PK, PV, CTX);
  out_kernel<<<(unsigned)(nrows / 32), 256, 0, stream>>>(CTX, x, Wo, Wout, bo, g1, b1, g2, b2, out);
}

// Round 2
// 428.595 us; speedup vs baseline: 2.6531x; 2.6531x over previous
//
#include <hip/hip_runtime.h>
#include <hip/hip_bf16.h>
#include <math.h>

constexpr int NB   = 4;
constexpr int LL   = 8192;
constexpr int DD   = 256;
constexpr int NH   = 8;
constexpr int HDIM = 32;
constexpr int WNN  = 9;
constexpr int PPAD = 4;

constexpr int CH  = 8;        // windows per attention block
constexpr int RS  = CH + 8;   // 16 staged rows
constexpr int SQS = 260;      // padded fp32 LDS stride in attn

typedef __attribute__((ext_vector_type(8))) short bf16x8;
typedef __attribute__((ext_vector_type(4))) float f32x4;

__device__ inline short f2bf(float f) {
  __hip_bfloat16 h = __float2bfloat16(f);
  short s; __builtin_memcpy(&s, &h, 2); return s;
}
__device__ inline float bf2f(short s) {
  unsigned u = ((unsigned)(unsigned short)s) << 16;
  float f; __builtin_memcpy(&f, &u, 4); return f;
}

// ---------------- x -> bf16 ----------------
__global__ __launch_bounds__(256) void conv_x(const float* __restrict__ x, short* __restrict__ XB) {
  size_t i = ((size_t)blockIdx.x * 256 + threadIdx.x) * 4;
  float4 v = *(const float4*)(x + i);
  short4 o; o.x = f2bf(v.x); o.y = f2bf(v.y); o.z = f2bf(v.z); o.w = f2bf(v.w);
  *(short4*)(XB + i) = o;
}

// ---------------- weights: Wq/Wk/Wv/Wo transposed->bf16 (n-major), Wout->bf16 straight ----------------
__global__ __launch_bounds__(256) void prep_w(
    const float* __restrict__ Wq, const float* __restrict__ Wk, const float* __restrict__ Wv,
    const float* __restrict__ Wo, const float* __restrict__ Wout,
    short* __restrict__ WqT, short* __restrict__ WkT, short* __restrict__ WvT,
    short* __restrict__ WoT, short* __restrict__ WoutB) {
  const int t = threadIdx.x, b = blockIdx.x;
  if (b < 4) {
    const float* W = (b == 0) ? Wq : (b == 1) ? Wk : (b == 2) ? Wv : Wo;
    short* T = (b == 0) ? WqT : (b == 1) ? WkT : (b == 2) ? WvT : WoT;
    for (int k = 0; k < 256; k += 4) {
      short4 o;
      o.x = f2bf(W[(size_t)(k + 0) * 256 + t]);
      o.y = f2bf(W[(size_t)(k + 1) * 256 + t]);
      o.z = f2bf(W[(size_t)(k + 2) * 256 + t]);
      o.w = f2bf(W[(size_t)(k + 3) * 256 + t]);
      *(short4*)&T[(size_t)t * 256 + k] = o;
    }
  } else {
    for (int i = t; i < 16384; i += 256) {
      float4 v = *(const float4*)(Wout + (size_t)i * 4);
      short4 o; o.x = f2bf(v.x); o.y = f2bf(v.y); o.z = f2bf(v.z); o.w = f2bf(v.w);
      *(short4*)(WoutB + (size_t)i * 4) = o;
    }
  }
}

// ---------------- pos projection (fp32, tiny) ----------------
__global__ __launch_bounds__(256) void pos_proj(
    const float* __restrict__ pos,
    const float* __restrict__ Wq, const float* __restrict__ Wk, const float* __restrict__ Wv,
    float* __restrict__ PQ, float* __restrict__ PK, float* __restrict__ PV) {
  __shared__ float ps[256];
  const int t = threadIdx.x, wrow = blockIdx.x, wh = blockIdx.y;
  const float* W = (wh == 0) ? Wq : (wh == 1) ? Wk : Wv;
  float* P = (wh == 0) ? PQ : (wh == 1) ? PK : PV;
  ps[t] = pos[wrow * 256 + t];
  __syncthreads();
  float a = 0.f;
  for (int d = 0; d < 256; ++d) a += ps[d] * W[(size_t)d * 256 + t];
  P[wrow * 256 + t] = a;
}

// ---------------- QKV projection via MFMA: XQ/XK/XV(bf16) = x @ W ----------------
// block: 64 rows x 256 cols, 4 waves, each wave 64x64 (4x4 16x16x32 tiles), frags from global
__global__ __launch_bounds__(256) void qkv_mfma(
    const short* __restrict__ XB,
    const short* __restrict__ WT0, const short* __restrict__ WT1, const short* __restrict__ WT2,
    short* __restrict__ O0, short* __restrict__ O1, short* __restrict__ O2) {
  const int t = threadIdx.x, w = t >> 6, lane = t & 63, q = lane >> 4, m = lane & 15;
  const size_t row0 = (size_t)blockIdx.x * 64;
  const short* WT = (blockIdx.y == 0) ? WT0 : (blockIdx.y == 1) ? WT1 : WT2;
  short* O = (blockIdx.y == 0) ? O0 : (blockIdx.y == 1) ? O1 : O2;

  f32x4 acc[4][4];
#pragma unroll
  for (int i = 0; i < 4; ++i)
#pragma unroll
    for (int j = 0; j < 4; ++j) acc[i][j] = (f32x4){0.f, 0.f, 0.f, 0.f};

  const short* abase = XB + (row0 + m) * (size_t)256 + q * 8;
  const short* bbase = WT + (size_t)(w * 64 + m) * 256 + q * 8;
#pragma unroll
  for (int kk = 0; kk < 8; ++kk) {
    bf16x8 a[4], b[4];
#pragma unroll
    for (int i = 0; i < 4; ++i) a[i] = *(const bf16x8*)(abase + (size_t)i * 16 * 256 + kk * 32);
#pragma unroll
    for (int j = 0; j < 4; ++j) b[j] = *(const bf16x8*)(bbase + (size_t)j * 16 * 256 + kk * 32);
#pragma unroll
    for (int i = 0; i < 4; ++i)
#pragma unroll
      for (int j = 0; j < 4; ++j)
        acc[i][j] = __builtin_amdgcn_mfma_f32_16x16x32_bf16(a[i], b[j], acc[i][j], 0, 0, 0);
  }
#pragma unroll
  for (int i = 0; i < 4; ++i)
#pragma unroll
    for (int j = 0; j < 4; ++j)
#pragma unroll
      for (int r = 0; r < 4; ++r) {
        size_t row = row0 + i * 16 + q * 4 + r;
        int col = w * 64 + j * 16 + m;
        O[row * 256 + col] = f2bf(acc[i][j][r]);
      }
}

// ---------------- windowed attention -> CTX (bf16 in/out) ----------------
__global__ __launch_bounds__(256) void attn_kernel(
    const short* __restrict__ XQb, const short* __restrict__ XKb, const short* __restrict__ XVb,
    const float* __restrict__ PQ, const float* __restrict__ PK, const float* __restrict__ PV,
    short* __restrict__ CTXB) {
  __shared__ float sq[RS * SQS];
  __shared__ float sk[RS * SQS];
  __shared__ float sv[RS * 256];
  __shared__ float pq[WNN * SQS];
  __shared__ float pk[WNN * SQS];
  __shared__ float pv[WNN * 256];
  __shared__ float asum[CH * NH * WNN];

  const int t = threadIdx.x;
  const int nblk = LL / CH;
  const int b = blockIdx.x / nblk;
  const int n0 = (blockIdx.x % nblk) * CH;
  const size_t base = (size_t)b * LL * DD;

  for (int w = 0; w < WNN; ++w) {
    pq[w * SQS + t] = PQ[w * DD + t];
    pk[w * SQS + t] = PK[w * DD + t];
    pv[w * 256 + t] = PV[w * DD + t];
  }
  for (int r = 0; r < RS; ++r) {
    int j = n0 - PPAD + r;
    float vq = 0.f, vk = 0.f, vv = 0.f;
    if (j >= 0 && j < LL) {
      size_t off = base + (size_t)j * DD + t;
      vq = bf2f(XQb[off]); vk = bf2f(XKb[off]); vv = bf2f(XVb[off]);
    }
    sq[r * SQS + t] = vq;
    sk[r * SQS + t] = vk;
    sv[r * 256 + t] = vv;
  }
  for (int i = t; i < CH * NH * WNN; i += 256) asum[i] = 0.f;
  __syncthreads();

  if (t < CH * NH * 3) {
    const int nl = t / 24;
    const int rem = t % 24;
    const int h = rem / 3;
    const int qg = rem % 3;
    float4 qv[3][8];
#pragma unroll
    for (int j = 0; j < 3; ++j) {
      const int qi = qg * 3 + j;
      const float4* qrow = (const float4*)&sq[(nl + qi) * SQS + h * HDIM];
      const float4* prow = (const float4*)&pq[qi * SQS + h * HDIM];
#pragma unroll
      for (int i = 0; i < 8; ++i) {
        float4 a = qrow[i], p = prow[i];
        qv[j][i] = make_float4(a.x + p.x, a.y + p.y, a.z + p.z, a.w + p.w);
      }
    }
    float sc[3][9];
#pragma unroll
    for (int ki = 0; ki < WNN; ++ki) {
      const float4* krow = (const float4*)&sk[(nl + ki) * SQS + h * HDIM];
      const float4* pkr  = (const float4*)&pk[ki * SQS + h * HDIM];
      float4 kv[8];
#pragma unroll
      for (int i = 0; i < 8; ++i) {
        float4 a = krow[i], p = pkr[i];
        kv[i] = make_float4(a.x + p.x, a.y + p.y, a.z + p.z, a.w + p.w);
      }
#pragma unroll
      for (int j = 0; j < 3; ++j) {
        float acc = 0.f;
#pragma unroll
        for (int i = 0; i < 8; ++i)
          acc += qv[j][i].x * kv[i].x + qv[j][i].y * kv[i].y +
                 qv[j][i].z * kv[i].z + qv[j][i].w * kv[i].w;
        sc[j][ki] = acc * 0.17677669529663687f;
      }
    }
#pragma unroll
    for (int j = 0; j < 3; ++j) {
      float mx = sc[j][0];
#pragma unroll
      for (int ki = 1; ki < WNN; ++ki) mx = fmaxf(mx, sc[j][ki]);
      float sum = 0.f;
#pragma unroll
      for (int ki = 0; ki < WNN; ++ki) { sc[j][ki] = __expf(sc[j][ki] - mx); sum += sc[j][ki]; }
      float inv = 1.f / sum;
#pragma unroll
      for (int ki = 0; ki < WNN; ++ki)
        atomicAdd(&asum[(nl * NH + h) * WNN + ki], sc[j][ki] * inv);
    }
  }
  __syncthreads();

  const int h = t >> 5;
  for (int nl = 0; nl < CH; ++nl) {
    float acc = 0.f;
#pragma unroll
    for (int ki = 0; ki < WNN; ++ki)
      acc += asum[(nl * NH + h) * WNN + ki] * (sv[(nl + ki) * 256 + t] + pv[ki * 256 + t]);
    CTXB[base + (size_t)(n0 + nl) * DD + t] = f2bf(acc);
  }
}

// ---------------- fused out stage via MFMA ----------------
__global__ __launch_bounds__(256) void out_mfma(
    const short* __restrict__ CTXB, const float* __restrict__ X,
    const short* __restrict__ WoT, const short* __restrict__ WoutB,
    const float* __restrict__ bo,
    const float* __restrict__ g1, const float* __restrict__ b1,
    const float* __restrict__ g2, const float* __restrict__ b2,
    float* __restrict__ out) {
  __shared__ short ar[64 * 264];          // bf16 attn_res tile, stride 264 (16B-aligned rows, 2-way banks)
  __shared__ float ws1[64][4], ws2[64][4];
  __shared__ float msh[64], rsh[64];
  __shared__ float g1s[256], b1s[256], g2s[256], b2s[256], bos[256];
  const int t = threadIdx.x, w = t >> 6, lane = t & 63, q = lane >> 4, m = lane & 15;
  const size_t row0 = (size_t)blockIdx.x * 64;
  g1s[t] = g1[t]; b1s[t] = b1[t]; g2s[t] = g2[t]; b2s[t] = b2[t]; bos[t] = bo[t];

  f32x4 acc[4][4];
#pragma unroll
  for (int i = 0; i < 4; ++i)
#pragma unroll
    for (int j = 0; j < 4; ++j) acc[i][j] = (f32x4){0.f, 0.f, 0.f, 0.f};

  // GEMM1: ctx @ Wo
  const short* abase = CTXB + (row0 + m) * (size_t)256 + q * 8;
  const short* bbase = WoT + (size_t)(w * 64 + m) * 256 + q * 8;
#pragma unroll
  for (int kk = 0; kk < 8; ++kk) {
    bf16x8 a[4], b[4];
#pragma unroll
    for (int i = 0; i < 4; ++i) a[i] = *(const bf16x8*)(abase + (size_t)i * 16 * 256 + kk * 32);
#pragma unroll
    for (int j = 0; j < 4; ++j) b[j] = *(const bf16x8*)(bbase + (size_t)j * 16 * 256 + kk * 32);
#pragma unroll
    for (int i = 0; i < 4; ++i)
#pragma unroll
      for (int j = 0; j < 4; ++j)
        acc[i][j] = __builtin_amdgcn_mfma_f32_16x16x32_bf16(a[i], b[j], acc[i][j], 0, 0, 0);
  }

  // + skip, LN1 partial stats
  float s1v[4][4], s2v[4][4];
#pragma unroll
  for (int i = 0; i < 4; ++i)
#pragma unroll
    for (int r = 0; r < 4; ++r) {
      float a0 = 0.f, b0 = 0.f;
#pragma unroll
      for (int j = 0; j < 4; ++j) {
        float v = acc[i][j][r] + X[(row0 + i * 16 + q * 4 + r) * 256 + w * 64 + j * 16 + m];
        acc[i][j][r] = v; a0 += v; b0 += v * v;
      }
      s1v[i][r] = a0; s2v[i][r] = b0;
    }
#pragma unroll
  for (int i = 0; i < 4; ++i)
#pragma unroll
    for (int r = 0; r < 4; ++r)
#pragma unroll
      for (int msk = 1; msk < 16; msk <<= 1) {
        s1v[i][r] += __shfl_xor(s1v[i][r], msk, 64);
        s2v[i][r] += __shfl_xor(s2v[i][r], msk, 64);
      }
  if (m == 0) {
#pragma unroll
    for (int i = 0; i < 4; ++i)
#pragma unroll
      for (int r = 0; r < 4; ++r) {
        ws1[i * 16 + q * 4 + r][w] = s1v[i][r];
        ws2[i * 16 + q * 4 + r][w] = s2v[i][r];
      }
  }
  __syncthreads();
  if (t < 64) {
    float a0 = 0.f, b0 = 0.f;
#pragma unroll
    for (int ww = 0; ww < 4; ++ww) { a0 += ws1[t][ww]; b0 += ws2[t][ww]; }
    float mean = a0 * (1.f / 256.f);
    float var = b0 * (1.f / 256.f) - mean * mean;
    msh[t] = mean; rsh[t] = rsqrtf(var + 1e-5f);
  }
  __syncthreads();

  // normalize -> ar (bf16 LDS)
#pragma unroll
  for (int i = 0; i < 4; ++i)
#pragma unroll
    for (int r = 0; r < 4; ++r) {
      int row = i * 16 + q * 4 + r;
      float mean = msh[row], rst = rsh[row];
#pragma unroll
      for (int j = 0; j < 4; ++j) {
        int col = w * 64 + j * 16 + m;
        float v = (acc[i][j][r] - mean) * rst * g1s[col] + b1s[col];
        ar[row * 264 + col] = f2bf(v);
      }
    }
  __syncthreads();

  // GEMM2: ar @ Wout^T  (B = Wout row-major is already n-major)
#pragma unroll
  for (int i = 0; i < 4; ++i)
#pragma unroll
    for (int j = 0; j < 4; ++j) acc[i][j] = (f32x4){0.f, 0.f, 0.f, 0.f};
  const short* b2base = WoutB + (size_t)(w * 64 + m) * 256 + q * 8;
#pragma unroll
  for (int kk = 0; kk < 8; ++kk) {
    bf16x8 a[4], b[4];
#pragma unroll
    for (int i = 0; i < 4; ++i) a[i] = *(const bf16x8*)&ar[(i * 16 + m) * 264 + kk * 32 + q * 8];
#pragma unroll
    for (int j = 0; j < 4; ++j) b[j] = *(const bf16x8*)(b2base + (size_t)j * 16 * 256 + kk * 32);
#pragma unroll
    for (int i = 0; i < 4; ++i)
#pragma unroll
      for (int j = 0; j < 4; ++j)
        acc[i][j] = __builtin_amdgcn_mfma_f32_16x16x32_bf16(a[i], b[j], acc[i][j], 0, 0, 0);
  }

  // + bias + residual, LN2 stats
#pragma unroll
  for (int i = 0; i < 4; ++i)
#pragma unroll
    for (int r = 0; r < 4; ++r) {
      int row = i * 16 + q * 4 + r;
      float a0 = 0.f, b0 = 0.f;
#pragma unroll
      for (int j = 0; j < 4; ++j) {
        int col = w * 64 + j * 16 + m;
        float v = acc[i][j][r] + bos[col] + bf2f(ar[row * 264 + col]);
        acc[i][j][r] = v; a0 += v; b0 += v * v;
      }
      s1v[i][r] = a0; s2v[i][r] = b0;
    }
#pragma unroll
  for (int i = 0; i < 4; ++i)
#pragma unroll
    for (int r = 0; r < 4; ++r)
#pragma unroll
      for (int msk = 1; msk < 16; msk <<= 1) {
        s1v[i][r] += __shfl_xor(s1v[i][r], msk, 64);
        s2v[i][r] += __shfl_xor(s2v[i][r], msk, 64);
      }
  if (m == 0) {
#pragma unroll
    for (int i = 0; i < 4; ++i)
#pragma unroll
      for (int r = 0; r < 4; ++r) {
        ws1[i * 16 + q * 4 + r][w] = s1v[i][r];
        ws2[i * 16 + q * 4 + r][w] = s2v[i][r];
      }
  }
  __syncthreads();
  if (t < 64) {
    float a0 = 0.f, b0 = 0.f;
#pragma unroll
    for (int ww = 0; ww < 4; ++ww) { a0 += ws1[t][ww]; b0 += ws2[t][ww]; }
    float mean = a0 * (1.f / 256.f);
    float var = b0 * (1.f / 256.f) - mean * mean;
    msh[t] = mean; rsh[t] = rsqrtf(var + 1e-5f);
  }
  __syncthreads();

  // normalize + relu + store
#pragma unroll
  for (int i = 0; i < 4; ++i)
#pragma unroll
    for (int r = 0; r < 4; ++r) {
      int row = i * 16 + q * 4 + r;
      float mean = msh[row], rst = rsh[row];
#pragma unroll
      for (int j = 0; j < 4; ++j) {
        int col = w * 64 + j * 16 + m;
        float v = (acc[i][j][r] - mean) * rst * g2s[col] + b2s[col];
        out[(row0 + row) * 256 + col] = fmaxf(v, 0.f);
      }
    }
}

extern "C" void kernel_launch(void* const* d_in, const int* in_sizes, int n_in,
                              void* d_out, int out_size, void* d_ws, size_t ws_size,
                              hipStream_t stream) {
  const float* x    = (const float*)d_in[0];
  const float* Wq   = (const float*)d_in[1];
  const float* Wk   = (const float*)d_in[2];
  const float* Wv   = (const float*)d_in[3];
  const float* Wo   = (const float*)d_in[4];
  const float* pos  = (const float*)d_in[5];
  const float* Wout = (const float*)d_in[6];
  const float* bo   = (const float*)d_in[7];
  const float* g1   = (const float*)d_in[8];
  const float* b1   = (const float*)d_in[9];
  const float* g2   = (const float*)d_in[10];
  const float* b2   = (const float*)d_in[11];
  float* out = (float*)d_out;

  const size_t nel = (size_t)NB * LL * DD;  // 8,388,608
  char* wsb = (char*)d_ws;
  short* XB   = (short*)wsb; wsb += nel * 2;
  short* XQb  = (short*)wsb; wsb += nel * 2;
  short* XKb  = (short*)wsb; wsb += nel * 2;
  short* XVb  = (short*)wsb; wsb += nel * 2;
  short* CTXB = (short*)wsb; wsb += nel * 2;
  short* WqT   = (short*)wsb; wsb += 65536 * 2;
  short* WkT   = (short*)wsb; wsb += 65536 * 2;
  short* WvT   = (short*)wsb; wsb += 65536 * 2;
  short* WoT   = (short*)wsb; wsb += 65536 * 2;
  short* WoutB = (short*)wsb; wsb += 65536 * 2;
  float* PQ = (float*)wsb; wsb += WNN * DD * 4;
  float* PK = (float*)wsb; wsb += WNN * DD * 4;
  float* PV = (float*)wsb; wsb += WNN * DD * 4;

  conv_x<<<(unsigned)(nel / 4 / 256), 256, 0, stream>>>(x, XB);
  prep_w<<<5, 256, 0, stream>>>(Wq, Wk, Wv, Wo, Wout, WqT, WkT, WvT, WoT, WoutB);
  pos_proj<<<dim3(WNN, 3), 256, 0, stream>>>(pos, Wq, Wk, Wv, PQ, PK, PV);
  qkv_mfma<<<dim3((unsigned)(NB * LL / 64), 3), 256, 0, stream>>>(XB, WqT, WkT, WvT, XQb, XKb, XVb);
  attn_kernel<<<NB * (LL / CH), 256, 0, stream>>>(XQb, XKb, XVb, PQ, PK, PV, CTXB);
  out_mfma<<<(unsigned)(NB * LL / 64), 256, 0, stream>>>(CTXB, x, WoT, WoutB, bo, g1, b1, g2, b2, out);
}

// Round 3
// 273.004 us; speedup vs baseline: 4.1651x; 1.5699x over previous
//
#include <hip/hip_runtime.h>
#include <hip/hip_bf16.h>
#include <math.h>

constexpr int NB   = 4;
constexpr int LL   = 8192;
constexpr int DD   = 256;
constexpr int NH   = 8;
constexpr int HDIM = 32;
constexpr int WNN  = 9;
constexpr int PPAD = 4;

constexpr int CW  = 32;         // windows per attention block
constexpr int RSN = CW + 8;     // 40 staged rows
constexpr int SST = 260;        // bf16 LDS row stride (dword stride 130 ≡ 2 mod 32 → bank spread)

typedef __attribute__((ext_vector_type(8))) short bf16x8;
typedef __attribute__((ext_vector_type(4))) float f32x4;

__device__ inline short f2bf(float f) {
  __hip_bfloat16 h = __float2bfloat16(f);
  short s; __builtin_memcpy(&s, &h, 2); return s;
}
__device__ inline float bf2f(short s) {
  unsigned u = ((unsigned)(unsigned short)s) << 16;
  float f; __builtin_memcpy(&f, &u, 4); return f;
}

// ---------------- x -> bf16 ----------------
__global__ __launch_bounds__(256) void conv_x(const float* __restrict__ x, short* __restrict__ XB) {
  size_t i = ((size_t)blockIdx.x * 256 + threadIdx.x) * 4;
  float4 v = *(const float4*)(x + i);
  short4 o; o.x = f2bf(v.x); o.y = f2bf(v.y); o.z = f2bf(v.z); o.w = f2bf(v.w);
  *(short4*)(XB + i) = o;
}

// ---------------- weights: Wq/Wk/Wv/Wo transposed->bf16 (n-major), Wout->bf16 straight ----------------
__global__ __launch_bounds__(256) void prep_w(
    const float* __restrict__ Wq, const float* __restrict__ Wk, const float* __restrict__ Wv,
    const float* __restrict__ Wo, const float* __restrict__ Wout,
    short* __restrict__ WqT, short* __restrict__ WkT, short* __restrict__ WvT,
    short* __restrict__ WoT, short* __restrict__ WoutB) {
  const int t = threadIdx.x, b = blockIdx.x;
  if (b < 4) {
    const float* W = (b == 0) ? Wq : (b == 1) ? Wk : (b == 2) ? Wv : Wo;
    short* T = (b == 0) ? WqT : (b == 1) ? WkT : (b == 2) ? WvT : WoT;
    for (int k = 0; k < 256; k += 4) {
      short4 o;
      o.x = f2bf(W[(size_t)(k + 0) * 256 + t]);
      o.y = f2bf(W[(size_t)(k + 1) * 256 + t]);
      o.z = f2bf(W[(size_t)(k + 2) * 256 + t]);
      o.w = f2bf(W[(size_t)(k + 3) * 256 + t]);
      *(short4*)&T[(size_t)t * 256 + k] = o;
    }
  } else {
    for (int i = t; i < 16384; i += 256) {
      float4 v = *(const float4*)(Wout + (size_t)i * 4);
      short4 o; o.x = f2bf(v.x); o.y = f2bf(v.y); o.z = f2bf(v.z); o.w = f2bf(v.w);
      *(short4*)(WoutB + (size_t)i * 4) = o;
    }
  }
}

// ---------------- pos projection (fp32 math, bf16 out) ----------------
__global__ __launch_bounds__(256) void pos_proj(
    const float* __restrict__ pos,
    const float* __restrict__ Wq, const float* __restrict__ Wk, const float* __restrict__ Wv,
    short* __restrict__ PQb, short* __restrict__ PKb, short* __restrict__ PVb) {
  __shared__ float ps[256];
  const int t = threadIdx.x, wrow = blockIdx.x, wh = blockIdx.y;
  const float* W = (wh == 0) ? Wq : (wh == 1) ? Wk : Wv;
  short* P = (wh == 0) ? PQb : (wh == 1) ? PKb : PVb;
  ps[t] = pos[wrow * 256 + t];
  __syncthreads();
  float a = 0.f;
  for (int d = 0; d < 256; ++d) a += ps[d] * W[(size_t)d * 256 + t];
  P[wrow * 256 + t] = f2bf(a);
}

// ---------------- QKV projection via MFMA with register-dbuf prefetch ----------------
__global__ __launch_bounds__(256) void qkv_mfma(
    const short* __restrict__ XB,
    const short* __restrict__ WT0, const short* __restrict__ WT1, const short* __restrict__ WT2,
    short* __restrict__ O0, short* __restrict__ O1, short* __restrict__ O2) {
  const int t = threadIdx.x, w = t >> 6, lane = t & 63, q = lane >> 4, m = lane & 15;
  const size_t row0 = (size_t)blockIdx.x * 64;
  const short* WT = (blockIdx.y == 0) ? WT0 : (blockIdx.y == 1) ? WT1 : WT2;
  short* O = (blockIdx.y == 0) ? O0 : (blockIdx.y == 1) ? O1 : O2;

  f32x4 acc[4][4];
#pragma unroll
  for (int i = 0; i < 4; ++i)
#pragma unroll
    for (int j = 0; j < 4; ++j) acc[i][j] = (f32x4){0.f, 0.f, 0.f, 0.f};

  const short* abase = XB + (row0 + m) * (size_t)256 + q * 8;
  const short* bbase = WT + (size_t)(w * 64 + m) * 256 + q * 8;
  bf16x8 a[4], b[4];
#pragma unroll
  for (int i = 0; i < 4; ++i) a[i] = *(const bf16x8*)(abase + (size_t)i * 4096);
#pragma unroll
  for (int j = 0; j < 4; ++j) b[j] = *(const bf16x8*)(bbase + (size_t)j * 4096);
#pragma unroll
  for (int kk = 0; kk < 8; ++kk) {
    bf16x8 an[4], bn[4];
    if (kk < 7) {
#pragma unroll
      for (int i = 0; i < 4; ++i) an[i] = *(const bf16x8*)(abase + (size_t)i * 4096 + (kk + 1) * 32);
#pragma unroll
      for (int j = 0; j < 4; ++j) bn[j] = *(const bf16x8*)(bbase + (size_t)j * 4096 + (kk + 1) * 32);
    }
#pragma unroll
    for (int i = 0; i < 4; ++i)
#pragma unroll
      for (int j = 0; j < 4; ++j)
        acc[i][j] = __builtin_amdgcn_mfma_f32_16x16x32_bf16(a[i], b[j], acc[i][j], 0, 0, 0);
    if (kk < 7) {
#pragma unroll
      for (int i = 0; i < 4; ++i) a[i] = an[i];
#pragma unroll
      for (int j = 0; j < 4; ++j) b[j] = bn[j];
    }
  }
#pragma unroll
  for (int i = 0; i < 4; ++i)
#pragma unroll
    for (int j = 0; j < 4; ++j)
#pragma unroll
      for (int r = 0; r < 4; ++r) {
        size_t row = row0 + i * 16 + q * 4 + r;
        int col = w * 64 + j * 16 + m;
        O[row * 256 + col] = f2bf(acc[i][j][r]);
      }
}

// ---------------- windowed attention v2: thread = (window, head) ----------------
__global__ __launch_bounds__(256, 2) void attn_kernel(
    const short* __restrict__ XQb, const short* __restrict__ XKb, const short* __restrict__ XVb,
    const short* __restrict__ PQb, const short* __restrict__ PKb, const short* __restrict__ PVb,
    short* __restrict__ CTXB) {
  __shared__ short sq[RSN * SST];
  __shared__ short sk[RSN * SST];
  __shared__ short sv[RSN * SST];
  __shared__ short pq[WNN * SST];
  __shared__ short pk[WNN * SST];
  __shared__ short pv[WNN * SST];

  const int t = threadIdx.x;
  const int nblk = LL / CW;
  const int b = blockIdx.x / nblk;
  const int n0 = (blockIdx.x % nblk) * CW;
  const size_t base = (size_t)b * LL * DD;

  // stage 40 halo rows of XQ/XK/XV (bf16, vectorized, coalesced)
#pragma unroll
  for (int i = 0; i < RSN * 64 / 256; ++i) {   // 10
    int idx = t + i * 256;
    int r = idx >> 6, c4 = (idx & 63) * 4;
    int j = n0 - PPAD + r;
    short4 vq = {0, 0, 0, 0}, vk = vq, vv = vq;
    if (j >= 0 && j < LL) {
      size_t off = base + (size_t)j * DD + c4;
      vq = *(const short4*)(XQb + off);
      vk = *(const short4*)(XKb + off);
      vv = *(const short4*)(XVb + off);
    }
    *(short4*)&sq[r * SST + c4] = vq;
    *(short4*)&sk[r * SST + c4] = vk;
    *(short4*)&sv[r * SST + c4] = vv;
  }
  // stage pos projections (9 rows)
#pragma unroll
  for (int i = 0; i < 3; ++i) {
    int idx = t + i * 256;
    if (idx < WNN * 64) {
      int r = idx >> 6, c4 = (idx & 63) * 4;
      *(short4*)&pq[r * SST + c4] = *(const short4*)(PQb + r * DD + c4);
      *(short4*)&pk[r * SST + c4] = *(const short4*)(PKb + r * DD + c4);
      *(short4*)&pv[r * SST + c4] = *(const short4*)(PVb + r * DD + c4);
    }
  }
  __syncthreads();

  const int n = t >> 3;        // window within block
  const int h = t & 7;         // head
  const int hoff = h * HDIM;

  float sc[WNN][WNN];
#pragma unroll
  for (int qi = 0; qi < WNN; ++qi)
#pragma unroll
    for (int ki = 0; ki < WNN; ++ki) sc[qi][ki] = 0.f;

  // scores: chunked K-dim so each q/k element is converted once, used 9x
#pragma unroll
  for (int c = 0; c < 8; ++c) {
    float qv[WNN][4], kv[WNN][4];
#pragma unroll
    for (int r = 0; r < WNN; ++r) {
      short4 xa = *(const short4*)&sq[(n + r) * SST + hoff + c * 4];
      short4 pa = *(const short4*)&pq[r * SST + hoff + c * 4];
      qv[r][0] = bf2f(xa.x) + bf2f(pa.x);
      qv[r][1] = bf2f(xa.y) + bf2f(pa.y);
      qv[r][2] = bf2f(xa.z) + bf2f(pa.z);
      qv[r][3] = bf2f(xa.w) + bf2f(pa.w);
      short4 xb = *(const short4*)&sk[(n + r) * SST + hoff + c * 4];
      short4 pb = *(const short4*)&pk[r * SST + hoff + c * 4];
      kv[r][0] = bf2f(xb.x) + bf2f(pb.x);
      kv[r][1] = bf2f(xb.y) + bf2f(pb.y);
      kv[r][2] = bf2f(xb.z) + bf2f(pb.z);
      kv[r][3] = bf2f(xb.w) + bf2f(pb.w);
    }
#pragma unroll
    for (int qi = 0; qi < WNN; ++qi)
#pragma unroll
      for (int ki = 0; ki < WNN; ++ki)
        sc[qi][ki] += qv[qi][0] * kv[ki][0] + qv[qi][1] * kv[ki][1] +
                      qv[qi][2] * kv[ki][2] + qv[qi][3] * kv[ki][3];
  }

  // softmax per q-row, accumulate column sums (all thread-local)
  float cs[WNN];
#pragma unroll
  for (int ki = 0; ki < WNN; ++ki) cs[ki] = 0.f;
  const float scale = 0.17677669529663687f;  // 1/sqrt(32)
#pragma unroll
  for (int qi = 0; qi < WNN; ++qi) {
    float mx = sc[qi][0];
#pragma unroll
    for (int ki = 1; ki < WNN; ++ki) mx = fmaxf(mx, sc[qi][ki]);
    float e[WNN], sum = 0.f;
#pragma unroll
    for (int ki = 0; ki < WNN; ++ki) { e[ki] = __expf((sc[qi][ki] - mx) * scale); sum += e[ki]; }
    float inv = 1.f / sum;
#pragma unroll
    for (int ki = 0; ki < WNN; ++ki) cs[ki] += e[ki] * inv;
  }

  // ctx: weighted sum of v rows (+ pos-v), write bf16
#pragma unroll
  for (int c = 0; c < 8; ++c) {
    float o0 = 0.f, o1 = 0.f, o2 = 0.f, o3 = 0.f;
#pragma unroll
    for (int ki = 0; ki < WNN; ++ki) {
      short4 xv4 = *(const short4*)&sv[(n + ki) * SST + hoff + c * 4];
      short4 pv4 = *(const short4*)&pv[ki * SST + hoff + c * 4];
      float wt = cs[ki];
      o0 += wt * (bf2f(xv4.x) + bf2f(pv4.x));
      o1 += wt * (bf2f(xv4.y) + bf2f(pv4.y));
      o2 += wt * (bf2f(xv4.z) + bf2f(pv4.z));
      o3 += wt * (bf2f(xv4.w) + bf2f(pv4.w));
    }
    short4 os; os.x = f2bf(o0); os.y = f2bf(o1); os.z = f2bf(o2); os.w = f2bf(o3);
    *(short4*)(CTXB + base + (size_t)(n0 + n) * DD + hoff + c * 4) = os;
  }
}

// CAUTION: softmax scale note — reference scales scores BEFORE softmax; we fold
// the scale into the exp argument ((sc-mx)*scale) which is equivalent since mx
// is the max of unscaled scores and scale>0.

// ---------------- fused out stage via MFMA ----------------
__global__ __launch_bounds__(256) void out_mfma(
    const short* __restrict__ CTXB, const float* __restrict__ X,
    const short* __restrict__ WoT, const short* __restrict__ WoutB,
    const float* __restrict__ bo,
    const float* __restrict__ g1, const float* __restrict__ b1,
    const float* __restrict__ g2, const float* __restrict__ b2,
    float* __restrict__ out) {
  __shared__ short ar[64 * 264];
  __shared__ float ws1[64][4], ws2[64][4];
  __shared__ float msh[64], rsh[64];
  __shared__ float g1s[256], b1s[256], g2s[256], b2s[256], bos[256];
  const int t = threadIdx.x, w = t >> 6, lane = t & 63, q = lane >> 4, m = lane & 15;
  const size_t row0 = (size_t)blockIdx.x * 64;
  g1s[t] = g1[t]; b1s[t] = b1[t]; g2s[t] = g2[t]; b2s[t] = b2[t]; bos[t] = bo[t];

  f32x4 acc[4][4];
#pragma unroll
  for (int i = 0; i < 4; ++i)
#pragma unroll
    for (int j = 0; j < 4; ++j) acc[i][j] = (f32x4){0.f, 0.f, 0.f, 0.f};

  // GEMM1: ctx @ Wo (register-dbuf prefetch)
  const short* abase = CTXB + (row0 + m) * (size_t)256 + q * 8;
  const short* bbase = WoT + (size_t)(w * 64 + m) * 256 + q * 8;
  {
    bf16x8 a[4], b[4];
#pragma unroll
    for (int i = 0; i < 4; ++i) a[i] = *(const bf16x8*)(abase + (size_t)i * 4096);
#pragma unroll
    for (int j = 0; j < 4; ++j) b[j] = *(const bf16x8*)(bbase + (size_t)j * 4096);
#pragma unroll
    for (int kk = 0; kk < 8; ++kk) {
      bf16x8 an[4], bn[4];
      if (kk < 7) {
#pragma unroll
        for (int i = 0; i < 4; ++i) an[i] = *(const bf16x8*)(abase + (size_t)i * 4096 + (kk + 1) * 32);
#pragma unroll
        for (int j = 0; j < 4; ++j) bn[j] = *(const bf16x8*)(bbase + (size_t)j * 4096 + (kk + 1) * 32);
      }
#pragma unroll
      for (int i = 0; i < 4; ++i)
#pragma unroll
        for (int j = 0; j < 4; ++j)
          acc[i][j] = __builtin_amdgcn_mfma_f32_16x16x32_bf16(a[i], b[j], acc[i][j], 0, 0, 0);
      if (kk < 7) {
#pragma unroll
        for (int i = 0; i < 4; ++i) a[i] = an[i];
#pragma unroll
        for (int j = 0; j < 4; ++j) b[j] = bn[j];
      }
    }
  }

  // + skip, LN1 partial stats
  float s1v[4][4], s2v[4][4];
#pragma unroll
  for (int i = 0; i < 4; ++i)
#pragma unroll
    for (int r = 0; r < 4; ++r) {
      float a0 = 0.f, b0 = 0.f;
#pragma unroll
      for (int j = 0; j < 4; ++j) {
        float v = acc[i][j][r] + X[(row0 + i * 16 + q * 4 + r) * 256 + w * 64 + j * 16 + m];
        acc[i][j][r] = v; a0 += v; b0 += v * v;
      }
      s1v[i][r] = a0; s2v[i][r] = b0;
    }
#pragma unroll
  for (int i = 0; i < 4; ++i)
#pragma unroll
    for (int r = 0; r < 4; ++r)
#pragma unroll
      for (int msk = 1; msk < 16; msk <<= 1) {
        s1v[i][r] += __shfl_xor(s1v[i][r], msk, 64);
        s2v[i][r] += __shfl_xor(s2v[i][r], msk, 64);
      }
  if (m == 0) {
#pragma unroll
    for (int i = 0; i < 4; ++i)
#pragma unroll
      for (int r = 0; r < 4; ++r) {
        ws1[i * 16 + q * 4 + r][w] = s1v[i][r];
        ws2[i * 16 + q * 4 + r][w] = s2v[i][r];
      }
  }
  __syncthreads();
  if (t < 64) {
    float a0 = 0.f, b0 = 0.f;
#pragma unroll
    for (int ww = 0; ww < 4; ++ww) { a0 += ws1[t][ww]; b0 += ws2[t][ww]; }
    float mean = a0 * (1.f / 256.f);
    float var = b0 * (1.f / 256.f) - mean * mean;
    msh[t] = mean; rsh[t] = rsqrtf(var + 1e-5f);
  }
  __syncthreads();

#pragma unroll
  for (int i = 0; i < 4; ++i)
#pragma unroll
    for (int r = 0; r < 4; ++r) {
      int row = i * 16 + q * 4 + r;
      float mean = msh[row], rst = rsh[row];
#pragma unroll
      for (int j = 0; j < 4; ++j) {
        int col = w * 64 + j * 16 + m;
        float v = (acc[i][j][r] - mean) * rst * g1s[col] + b1s[col];
        ar[row * 264 + col] = f2bf(v);
      }
    }
  __syncthreads();

  // GEMM2: ar @ Wout^T (A from LDS, B global with prefetch)
#pragma unroll
  for (int i = 0; i < 4; ++i)
#pragma unroll
    for (int j = 0; j < 4; ++j) acc[i][j] = (f32x4){0.f, 0.f, 0.f, 0.f};
  const short* b2base = WoutB + (size_t)(w * 64 + m) * 256 + q * 8;
  {
    bf16x8 b[4];
#pragma unroll
    for (int j = 0; j < 4; ++j) b[j] = *(const bf16x8*)(b2base + (size_t)j * 4096);
#pragma unroll
    for (int kk = 0; kk < 8; ++kk) {
      bf16x8 bn[4];
      if (kk < 7) {
#pragma unroll
        for (int j = 0; j < 4; ++j) bn[j] = *(const bf16x8*)(b2base + (size_t)j * 4096 + (kk + 1) * 32);
      }
      bf16x8 a[4];
#pragma unroll
      for (int i = 0; i < 4; ++i) a[i] = *(const bf16x8*)&ar[(i * 16 + m) * 264 + kk * 32 + q * 8];
#pragma unroll
      for (int i = 0; i < 4; ++i)
#pragma unroll
        for (int j = 0; j < 4; ++j)
          acc[i][j] = __builtin_amdgcn_mfma_f32_16x16x32_bf16(a[i], b[j], acc[i][j], 0, 0, 0);
      if (kk < 7) {
#pragma unroll
        for (int j = 0; j < 4; ++j) b[j] = bn[j];
      }
    }
  }

  // + bias + residual, LN2 stats
#pragma unroll
  for (int i = 0; i < 4; ++i)
#pragma unroll
    for (int r = 0; r < 4; ++r) {
      int row = i * 16 + q * 4 + r;
      float a0 = 0.f, b0 = 0.f;
#pragma unroll
      for (int j = 0; j < 4; ++j) {
        int col = w * 64 + j * 16 + m;
        float v = acc[i][j][r] + bos[col] + bf2f(ar[row * 264 + col]);
        acc[i][j][r] = v; a0 += v; b0 += v * v;
      }
      s1v[i][r] = a0; s2v[i][r] = b0;
    }
#pragma unroll
  for (int i = 0; i < 4; ++i)
#pragma unroll
    for (int r = 0; r < 4; ++r)
#pragma unroll
      for (int msk = 1; msk < 16; msk <<= 1) {
        s1v[i][r] += __shfl_xor(s1v[i][r], msk, 64);
        s2v[i][r] += __shfl_xor(s2v[i][r], msk, 64);
      }
  if (m == 0) {
#pragma unroll
    for (int i = 0; i < 4; ++i)
#pragma unroll
      for (int r = 0; r < 4; ++r) {
        ws1[i * 16 + q * 4 + r][w] = s1v[i][r];
        ws2[i * 16 + q * 4 + r][w] = s2v[i][r];
      }
  }
  __syncthreads();
  if (t < 64) {
    float a0 = 0.f, b0 = 0.f;
#pragma unroll
    for (int ww = 0; ww < 4; ++ww) { a0 += ws1[t][ww]; b0 += ws2[t][ww]; }
    float mean = a0 * (1.f / 256.f);
    float var = b0 * (1.f / 256.f) - mean * mean;
    msh[t] = mean; rsh[t] = rsqrtf(var + 1e-5f);
  }
  __syncthreads();

#pragma unroll
  for (int i = 0; i < 4; ++i)
#pragma unroll
    for (int r = 0; r < 4; ++r) {
      int row = i * 16 + q * 4 + r;
      float mean = msh[row], rst = rsh[row];
#pragma unroll
      for (int j = 0; j < 4; ++j) {
        int col = w * 64 + j * 16 + m;
        float v = (acc[i][j][r] - mean) * rst * g2s[col] + b2s[col];
        out[(row0 + row) * 256 + col] = fmaxf(v, 0.f);
      }
    }
}

extern "C" void kernel_launch(void* const* d_in, const int* in_sizes, int n_in,
                              void* d_out, int out_size, void* d_ws, size_t ws_size,
                              hipStream_t stream) {
  const float* x    = (const float*)d_in[0];
  const float* Wq   = (const float*)d_in[1];
  const float* Wk   = (const float*)d_in[2];
  const float* Wv   = (const float*)d_in[3];
  const float* Wo   = (const float*)d_in[4];
  const float* pos  = (const float*)d_in[5];
  const float* Wout = (const float*)d_in[6];
  const float* bo   = (const float*)d_in[7];
  const float* g1   = (const float*)d_in[8];
  const float* b1   = (const float*)d_in[9];
  const float* g2   = (const float*)d_in[10];
  const float* b2   = (const float*)d_in[11];
  float* out = (float*)d_out;

  const size_t nel = (size_t)NB * LL * DD;
  char* wsb = (char*)d_ws;
  short* XB   = (short*)wsb; wsb += nel * 2;
  short* XQb  = (short*)wsb; wsb += nel * 2;
  short* XKb  = (short*)wsb; wsb += nel * 2;
  short* XVb  = (short*)wsb; wsb += nel * 2;
  short* CTXB = (short*)wsb; wsb += nel * 2;
  short* WqT   = (short*)wsb; wsb += 65536 * 2;
  short* WkT   = (short*)wsb; wsb += 65536 * 2;
  short* WvT   = (short*)wsb; wsb += 65536 * 2;
  short* WoT   = (short*)wsb; wsb += 65536 * 2;
  short* WoutB = (short*)wsb; wsb += 65536 * 2;
  short* PQb = (short*)wsb; wsb += WNN * DD * 2;
  short* PKb = (short*)wsb; wsb += WNN * DD * 2;
  short* PVb = (short*)wsb; wsb += WNN * DD * 2;

  conv_x<<<(unsigned)(nel / 4 / 256), 256, 0, stream>>>(x, XB);
  prep_w<<<5, 256, 0, stream>>>(Wq, Wk, Wv, Wo, Wout, WqT, WkT, WvT, WoT, WoutB);
  pos_proj<<<dim3(WNN, 3), 256, 0, stream>>>(pos, Wq, Wk, Wv, PQb, PKb, PVb);
  qkv_mfma<<<dim3((unsigned)(NB * LL / 64), 3), 256, 0, stream>>>(XB, WqT, WkT, WvT, XQb, XKb, XVb);
  attn_kernel<<<NB * (LL / CW), 256, 0, stream>>>(XQb, XKb, XVb, PQb, PKb, PVb, CTXB);
  out_mfma<<<(unsigned)(NB * LL / 64), 256, 0, stream>>>(CTXB, x, WoT, WoutB, bo, g1, b1, g2, b2, out);
}